// Round 2
// baseline (433.500 us; speedup 1.0000x reference)
//
#include <hip/hip_runtime.h>

// SparseCodebook: out[b] = min_k mean_d |codes[b,d] - centroids[cls[b],k,d]|
// B=262144, NUM_CLASSES=1000, K=4, D=256.
//
// R4: centroids fp32->fp16 in d_ws (2 MB table; gather bytes halve to 512 MB).
// R5: whole-wave-per-sample layout (coalesced 1 KiB codes loads, 512 B
//     contiguous gathers, SPW=8). NEUTRAL -> not VMEM-transaction-bound.
// R6 theory: the remaining cost is the 537 MB gather stream itself falling
// out of L2 under codes-stream pressure. Eliminate it: counting-sort samples
// by class (hist -> scan -> scatter, ~15 us on 1 MB data), then each wave
// processes 8 same-class samples and loads the 2 KB class block ONCE behind
// a wave-uniform branch. Gather traffic 537 MB -> ~67 MB. Compute/reduction
// identical to R5 for attribution.
// Predict: total 370 -> ~325-340 us if gathers were the residual; neutral
// means main kernel is at its codes-stream floor -> ROOFLINE call next.

#define B_TOTAL     262144
#define NUM_CLASSES 1000
#define KC          4
#define DIM         256
#define SPW         8   // samples per wave

typedef float    vf4 __attribute__((ext_vector_type(4)));
typedef _Float16 vh4 __attribute__((ext_vector_type(4)));

// ws layout (bytes):
//   [0, 2,048,000)        fp16 centroid table
//   [2 MiB, +4 KiB)       hist[1000]
//   [2 MiB+4K, +4 KiB)    offs[1000]
//   [2 MiB+8K, +1 MiB)    sorted keys: idx | (cls<<18)
#define WS_TAB_OFF   0
#define WS_HIST_OFF  2097152
#define WS_OFFS_OFF  (2097152 + 4096)
#define WS_SORT_OFF  (2097152 + 8192)

// centroids fp32 -> fp16 into ws. 1000*4*256 = 1,024,000 elems = 256,000 vf4.
__global__ __launch_bounds__(256) void convert_kernel(
    const float* __restrict__ cent_f32, _Float16* __restrict__ cent_f16)
{
    const int i = blockIdx.x * 256 + threadIdx.x;           // vf4 index
    const int n = NUM_CLASSES * KC * DIM / 4;               // 256,000
    if (i < n) {
        const vf4 v = ((const vf4*)cent_f32)[i];
        vh4 h;
        h.x = (_Float16)v.x; h.y = (_Float16)v.y;
        h.z = (_Float16)v.z; h.w = (_Float16)v.w;
        ((vh4*)cent_f16)[i] = h;
    }
}

// Per-block LDS histogram -> global atomics. Grid covers B exactly.
__global__ __launch_bounds__(256) void hist_kernel(
    const int* __restrict__ pred, int* __restrict__ hist)
{
    __shared__ int lh[NUM_CLASSES];
    for (int c = threadIdx.x; c < NUM_CLASSES; c += 256) lh[c] = 0;
    __syncthreads();
    const int i = blockIdx.x * 256 + threadIdx.x;
    atomicAdd(&lh[pred[i]], 1);
    __syncthreads();
    for (int c = threadIdx.x; c < NUM_CLASSES; c += 256) {
        const int v = lh[c];
        if (v) atomicAdd(&hist[c], v);
    }
}

// Single-block exclusive scan over 1000 bins (Hillis-Steele in LDS).
__global__ __launch_bounds__(1024) void scan_kernel(
    const int* __restrict__ hist, int* __restrict__ offs)
{
    __shared__ int sh[1024];
    const int t = threadIdx.x;
    const int h = (t < NUM_CLASSES) ? hist[t] : 0;
    sh[t] = h;
    __syncthreads();
    for (int off = 1; off < 1024; off <<= 1) {
        const int v = (t >= off) ? sh[t - off] : 0;
        __syncthreads();
        sh[t] += v;
        __syncthreads();
    }
    if (t < NUM_CLASSES) offs[t] = sh[t] - h;   // exclusive prefix
}

// Scatter packed keys into class-sorted order. Order within a class is
// atomic-race-nondeterministic -- irrelevant, output is keyed by idx.
__global__ __launch_bounds__(256) void scatter_kernel(
    const int* __restrict__ pred, int* __restrict__ offs,
    unsigned* __restrict__ sorted)
{
    const int i = blockIdx.x * 256 + threadIdx.x;
    const int c = pred[i];
    const int r = atomicAdd(&offs[c], 1);
    sorted[r] = (unsigned)i | ((unsigned)c << 18);   // idx<2^18, cls<2^10
}

// One sample per wave slot; lane l covers dims [4l, 4l+4). SPW samples per
// wave in class-sorted order: the 2 KB class block is loaded once per class
// run (wave-uniform branch) and reused from registers.
__global__ __launch_bounds__(256) void sparse_codebook_s(
    const float*    __restrict__ codes,
    const unsigned* __restrict__ sorted,
    const _Float16* __restrict__ cent_f16,
    float*          __restrict__ out)
{
    const int wave = (blockIdx.x * 256 + threadIdx.x) >> 6;
    const int lane = threadIdx.x & 63;
    const int s0   = wave * SPW;

    unsigned e[SPW];
#pragma unroll
    for (int s = 0; s < SPW; ++s)
        e[s] = sorted[s0 + s];

    const vf4* cv = (const vf4*)codes;
    vf4 c_next = __builtin_nontemporal_load(
        &cv[(size_t)(e[0] & 0x3FFFFu) * 64 + lane]);

    int cur_cls = -1;
    vh4 g0, g1, g2, g3;

#pragma unroll
    for (int s = 0; s < SPW; ++s) {
        const vf4 c = c_next;
        if (s + 1 < SPW)
            c_next = __builtin_nontemporal_load(
                &cv[(size_t)(e[s + 1] & 0x3FFFFu) * 64 + lane]);

        const int cls = (int)(e[s] >> 18);
        if (cls != cur_cls) {                     // wave-uniform branch
            const vh4* cb = (const vh4*)cent_f16
                          + (size_t)cls * (KC * DIM / 4) + lane;
            g0 = cb[0];
            g1 = cb[64];
            g2 = cb[128];
            g3 = cb[192];
            cur_cls = cls;
        }

        float d0 = fabsf(c.x - (float)g0.x) + fabsf(c.y - (float)g0.y)
                 + fabsf(c.z - (float)g0.z) + fabsf(c.w - (float)g0.w);
        float d1 = fabsf(c.x - (float)g1.x) + fabsf(c.y - (float)g1.y)
                 + fabsf(c.z - (float)g1.z) + fabsf(c.w - (float)g1.w);
        float d2 = fabsf(c.x - (float)g2.x) + fabsf(c.y - (float)g2.y)
                 + fabsf(c.z - (float)g2.z) + fabsf(c.w - (float)g2.w);
        float d3 = fabsf(c.x - (float)g3.x) + fabsf(c.y - (float)g3.y)
                 + fabsf(c.z - (float)g3.z) + fabsf(c.w - (float)g3.w);

        // k-interleaved butterfly: 9 shuffles total (identical to R5).
        const bool b0 = (lane & 1) != 0;
        const bool b1 = (lane & 2) != 0;
        float ka = b0 ? d1 : d0;
        float kb = b0 ? d0 : d1;
        ka += __shfl_xor(kb, 1, 64);
        float kc = b0 ? d3 : d2;
        float kd = b0 ? d2 : d3;
        kc += __shfl_xor(kd, 1, 64);
        float ke = b1 ? kc : ka;
        float kf = b1 ? ka : kc;
        ke += __shfl_xor(kf, 2, 64);
        ke += __shfl_xor(ke, 4, 64);
        ke += __shfl_xor(ke, 8, 64);
        ke += __shfl_xor(ke, 16, 64);
        ke += __shfl_xor(ke, 32, 64);
        float m = fminf(ke, __shfl_xor(ke, 1, 64));
        m = fminf(m, __shfl_xor(m, 2, 64));

        if (lane == 0)
            __builtin_nontemporal_store(m * (1.0f / (float)DIM),
                                        &out[e[s] & 0x3FFFFu]);
    }
}

extern "C" void kernel_launch(void* const* d_in, const int* in_sizes, int n_in,
                              void* d_out, int out_size, void* d_ws, size_t ws_size,
                              hipStream_t stream) {
    const float* codes = (const float*)d_in[0];
    const int*   pred  = (const int*)d_in[1];
    const float* cents = (const float*)d_in[2];
    float*       out   = (float*)d_out;

    char*      ws     = (char*)d_ws;
    _Float16*  tab    = (_Float16*)(ws + WS_TAB_OFF);
    int*       hist   = (int*)(ws + WS_HIST_OFF);
    int*       offs   = (int*)(ws + WS_OFFS_OFF);
    unsigned*  sorted = (unsigned*)(ws + WS_SORT_OFF);

    hipMemsetAsync(hist, 0, 4096, stream);

    const int nvec = NUM_CLASSES * KC * DIM / 4;  // 256,000
    convert_kernel<<<(nvec + 255) / 256, 256, 0, stream>>>(cents, tab);

    hist_kernel<<<B_TOTAL / 256, 256, 0, stream>>>(pred, hist);
    scan_kernel<<<1, 1024, 0, stream>>>(hist, offs);
    scatter_kernel<<<B_TOTAL / 256, 256, 0, stream>>>(pred, offs, sorted);

    const int waves  = B_TOTAL / SPW;             // 32768
    const int blocks = (waves * 64) / 256;        // 8192
    sparse_codebook_s<<<blocks, 256, 0, stream>>>(codes, sorted, tab, out);
}

// Round 3
// 361.009 us; speedup vs baseline: 1.2008x; 1.2008x over previous
//
#include <hip/hip_runtime.h>

// SparseCodebook: out[b] = min_k mean_d |codes[b,d] - centroids[cls[b],k,d]|
// B=262144, NUM_CLASSES=1000, K=4, D=256.
//
// R3 post-mortem: instruction restructuring is neutral -> BW-bound. Kernel
// moves 256 MiB codes (compulsory HBM) + centroid gathers; the fp32 table
// thrashes the 4 MiB/XCD L2 under stream pressure.
// R4: centroids fp32->fp16 into d_ws (2 MB table, L2-resident even under
// streaming; gather bytes halve to 512 MB). BEST: 362-363 us.
// R5 (whole-wave layout, coalesced 1 KiB codes loads): NEUTRAL (370) ->
//   not VMEM-transaction-bound.
// R6 (class-sort + per-class block reuse): REGRESSED (433) -> sort overhead
//   + random-order codes stream cost >> gather savings.
// R7: REVERT to R4. Decomposition: timed region ~= 2x161 us harness poison
// fills + ~5 us convert + main ~43 us == 256 MiB codes @ 6.3 TB/s = 42.6 us
// compulsory floor. Main kernel is at its memory roofline.

#define B_TOTAL     262144
#define NUM_CLASSES 1000
#define KC          4
#define DIM         256

typedef float    vf4 __attribute__((ext_vector_type(4)));
typedef _Float16 vh4 __attribute__((ext_vector_type(4)));

// centroids fp32 -> fp16 into ws. 1000*4*256 = 1,024,000 elems = 256,000 vf4.
__global__ __launch_bounds__(256) void convert_kernel(
    const float* __restrict__ cent_f32, _Float16* __restrict__ cent_f16)
{
    const int i = blockIdx.x * 256 + threadIdx.x;           // vf4 index
    const int n = NUM_CLASSES * KC * DIM / 4;               // 256,000
    if (i < n) {
        const vf4 v = ((const vf4*)cent_f32)[i];
        vh4 h;
        h.x = (_Float16)v.x; h.y = (_Float16)v.y;
        h.z = (_Float16)v.z; h.w = (_Float16)v.w;
        ((vh4*)cent_f16)[i] = h;
    }
}

// 4 samples per wave; each 16-lane quarter owns one sample.
// Lane covers dims [4*(j*16+l), +4) for j=0..3.
__global__ __launch_bounds__(256) void sparse_codebook_h(
    const float*    __restrict__ codes,
    const int*      __restrict__ pred_class,
    const _Float16* __restrict__ cent_f16,
    float*          __restrict__ out)
{
    const int wave = (blockIdx.x * 256 + threadIdx.x) >> 6;
    const int lane = threadIdx.x & 63;
    const int q    = lane >> 4;
    const int l    = lane & 15;
    const int s0   = wave * 4;
    if (s0 >= B_TOTAL) return;

    const int my_sample = s0 + q;
    const int cls = pred_class[my_sample];

    // codes row: 64 vf4 chunks; nontemporal (one-pass stream, keep L2 for table)
    const vf4* crow = (const vf4*)codes + (size_t)my_sample * 64;
    vf4 c[4];
#pragma unroll
    for (int j = 0; j < 4; ++j)
        c[j] = __builtin_nontemporal_load(&crow[j * 16 + l]);

    // fp16 class block: KC rows x 64 vh4 chunks (8 B/lane gathers, L2-resident)
    const vh4* cbase = (const vh4*)cent_f16 + (size_t)cls * (KC * DIM / 4);

    float s[KC];
#pragma unroll
    for (int k = 0; k < KC; ++k) {
        float acc = 0.0f;
#pragma unroll
        for (int j = 0; j < 4; ++j) {
            const vh4 g = cbase[k * 64 + j * 16 + l];
            acc += fabsf(c[j].x - (float)g.x) + fabsf(c[j].y - (float)g.y)
                 + fabsf(c[j].z - (float)g.z) + fabsf(c[j].w - (float)g.w);
        }
        s[k] = acc;
    }

    // reduce across the 16 lanes of this quarter (xor masks stay in-quarter)
#pragma unroll
    for (int off = 8; off >= 1; off >>= 1) {
#pragma unroll
        for (int k = 0; k < KC; ++k)
            s[k] += __shfl_xor(s[k], off, 64);
    }

    if (l == 0) {
        const float m = fminf(fminf(s[0], s[1]), fminf(s[2], s[3]));
        __builtin_nontemporal_store(m * (1.0f / (float)DIM), &out[my_sample]);
    }
}

extern "C" void kernel_launch(void* const* d_in, const int* in_sizes, int n_in,
                              void* d_out, int out_size, void* d_ws, size_t ws_size,
                              hipStream_t stream) {
    const float* codes = (const float*)d_in[0];
    const int*   pred  = (const int*)d_in[1];
    const float* cents = (const float*)d_in[2];
    float*       out   = (float*)d_out;
    _Float16*    tab   = (_Float16*)d_ws;   // 2 MB fp16 centroid table

    const int nvec = NUM_CLASSES * KC * DIM / 4;  // 256,000
    convert_kernel<<<(nvec + 255) / 256, 256, 0, stream>>>(cents, tab);

    const int grid = (B_TOTAL * 16) / 256;        // 4 samples/wave -> 16384
    sparse_codebook_h<<<grid, 256, 0, stream>>>(codes, pred, tab, out);
}